// Round 3
// baseline (8718.896 us; speedup 1.0000x reference)
//
#include <hip/hip_runtime.h>
#include <math.h>

#define LATENT   1024
#define WORD     64
#define NB_WORD  8192
#define BATCH    2048
#define NROWS    (BATCH * LATENT / WORD)   // 32768
#define NELEM    (BATCH * LATENT)          // 2097152

#define BM       128                       // rows per block
#define BN       256                       // codewords per tile
#define NT       (NB_WORD / BN)            // 32 tiles
#define NPH      (2 * NT)                  // 64 half-phases (k split 2x32)

// ---------------- kernel 1: e2[m] = sum_k emb[m][k]^2 ----------------
__global__ __launch_bounds__(256) void vq_e2_kernel(
    const float* __restrict__ emb, float* __restrict__ e2) {
    int m = blockIdx.x * 256 + threadIdx.x;
    if (m >= NB_WORD) return;
    const float4* ep = reinterpret_cast<const float4*>(emb + (size_t)m * WORD);
    float s0 = 0.f, s1 = 0.f, s2 = 0.f, s3 = 0.f;
#pragma unroll
    for (int i = 0; i < 16; ++i) {
        float4 v = ep[i];
        s0 = fmaf(v.x, v.x, s0);
        s1 = fmaf(v.y, v.y, s1);
        s2 = fmaf(v.z, v.z, s2);
        s3 = fmaf(v.w, v.w, s3);
    }
    e2[m] = (s0 + s1) + (s2 + s3);
}

// async 16B global -> LDS
__device__ __forceinline__ void gload_lds16(const float* g, float* l) {
    __builtin_amdgcn_global_load_lds(
        (const __attribute__((address_space(1))) void*)g,
        (__attribute__((address_space(3))) void*)l, 16, 0, 0);
}

// ---------------- kernel 2: tiled register-blocked argmin -------------
// 512 threads. Lane (c = tid&15, rl = tid>>4). Each thread: 4 rows x 16 cw.
// z: LDS [128 rows][16 f4], slot kk^(row&15).  e: LDS dbuf [256 cw][8 f4]
// per 32-k half, slot kk^(cw&7), staged by global_load_lds with
// pre-swizzled global source addresses.
__global__ __launch_bounds__(512, 2) void vq_argmin_kernel(
    const float* __restrict__ z, const float* __restrict__ emb,
    const float* __restrict__ e2, unsigned long long* __restrict__ best) {

    __shared__ float lz[BM * 64];          // 32 KB
    __shared__ float le[2][BN * 32];       // 2 x 32 KB

    const int tid = threadIdx.x;
    const int c   = tid & 15;
    const int rl  = tid >> 4;              // 0..31, owns rows rl*4..rl*4+3
    const int rowbase = blockIdx.x * BM;

    // ---- stage z (swizzled ds_write) ----
#pragma unroll
    for (int j = 0; j < 4; ++j) {
        int slot = j * 512 + tid;          // f4 slot 0..2047
        int row = slot >> 4, kk = slot & 15;
        float4 v = reinterpret_cast<const float4*>(z)[(size_t)(rowbase + row) * 16 + kk];
        *reinterpret_cast<float4*>(&lz[(row * 16 + (kk ^ (row & 15))) * 4]) = v;
    }

    // ---- stage e half-tile 0 into buf 0 ----
    {
#pragma unroll
        for (int j = 0; j < 4; ++j) {
            int slot = j * 512 + tid;      // f4 slot 0..2047 in half-tile
            int cw = slot >> 3, kk = slot & 7;
            const float* gp = emb + ((size_t)cw * 16 + (kk ^ (cw & 7))) * 4;
            float* lp = &le[0][(size_t)(j * 512 + (tid & ~63)) * 4];
            gload_lds16(gp, lp);
        }
    }
    __syncthreads();

    // ---- per-thread z2 for its 4 rows (same summation order as before) ----
    float z2v[4];
#pragma unroll
    for (int i = 0; i < 4; ++i) {
        int row = rl * 4 + i;
        float a0 = 0.f, a1 = 0.f, a2 = 0.f, a3 = 0.f;
#pragma unroll
        for (int g = 0; g < 16; ++g) {
            float4 v = *reinterpret_cast<const float4*>(
                &lz[(row * 16 + (g ^ (row & 15))) * 4]);
            a0 = fmaf(v.x, v.x, a0);
            a1 = fmaf(v.y, v.y, a1);
            a2 = fmaf(v.z, v.z, a2);
            a3 = fmaf(v.w, v.w, a3);
        }
        z2v[i] = (a0 + a1) + (a2 + a3);
    }

    float bestd[4] = {INFINITY, INFINITY, INFINITY, INFINITY};
    int   bestm[4] = {0, 0, 0, 0};
    float acc[4][16];
    float e2r[16];

#pragma unroll 2
    for (int ht = 0; ht < NPH; ++ht) {
        const int t   = ht >> 1;
        const int h   = ht & 1;
        const int buf = ht & 1;

        // issue next half-tile stage (overlaps with compute below)
        if (ht + 1 < NPH) {
            const int t1 = (ht + 1) >> 1, h1 = (ht + 1) & 1, b1 = (ht + 1) & 1;
#pragma unroll
            for (int j = 0; j < 4; ++j) {
                int slot = j * 512 + tid;
                int cw = slot >> 3, kk = slot & 7;
                const float* gp = emb +
                    ((size_t)(t1 * BN + cw) * 16 + h1 * 8 + (kk ^ (cw & 7))) * 4;
                float* lp = &le[b1][(size_t)(j * 512 + (tid & ~63)) * 4];
                gload_lds16(gp, lp);
            }
        }

        if (h == 0) {
#pragma unroll
            for (int s = 0; s < 16; ++s) e2r[s] = e2[t * BN + c + 16 * s];
#pragma unroll
            for (int i = 0; i < 4; ++i)
#pragma unroll
                for (int s = 0; s < 16; ++s) acc[i][s] = 0.f;
        }

        // ---- compute: 8 4-k groups over this half's 256 codewords ----
#pragma unroll
        for (int g = 0; g < 8; ++g) {
            float4 za[4];
            const int gg = h * 8 + g;
#pragma unroll
            for (int i = 0; i < 4; ++i) {
                int row = rl * 4 + i;
                za[i] = *reinterpret_cast<const float4*>(
                    &lz[(row * 16 + (gg ^ (row & 15))) * 4]);
            }
#pragma unroll
            for (int s = 0; s < 16; ++s) {
                int cw = c + 16 * s;
                float4 ev = *reinterpret_cast<const float4*>(
                    &le[buf][(cw * 8 + (g ^ (c & 7))) * 4]);
#pragma unroll
                for (int i = 0; i < 4; ++i) {
                    acc[i][s] = fmaf(za[i].x, ev.x, acc[i][s]);
                    acc[i][s] = fmaf(za[i].y, ev.y, acc[i][s]);
                    acc[i][s] = fmaf(za[i].z, ev.z, acc[i][s]);
                    acc[i][s] = fmaf(za[i].w, ev.w, acc[i][s]);
                }
            }
        }

        // ---- fold argmin at tile end (registers only, before barrier) ----
        if (h == 1) {
#pragma unroll
            for (int s = 0; s < 16; ++s) {
                int m = t * BN + c + 16 * s;
#pragma unroll
                for (int i = 0; i < 4; ++i) {
                    float d = fmaf(-2.0f, acc[i][s], z2v[i] + e2r[s]);
                    if (d < bestd[i]) { bestd[i] = d; bestm[i] = m; }
                }
            }
        }

        __syncthreads();   // drains our gload_lds (vmcnt) + all ds reads
    }

    // ---- cross-lane min over the 16 c-lanes sharing each row ----
#pragma unroll
    for (int i = 0; i < 4; ++i) {
        unsigned int db = __float_as_uint(bestd[i]);
        db = (db & 0x80000000u) ? ~db : (db | 0x80000000u);
        unsigned long long key =
            ((unsigned long long)db << 32) | (unsigned int)bestm[i];
#pragma unroll
        for (int off = 1; off < 16; off <<= 1) {
            unsigned long long o = __shfl_xor(key, off);
            key = (o < key) ? o : key;
        }
        if (c == 0) best[rowbase + rl * 4 + i] = key;
    }
}

// ---------------- kernel 3: gather + straight-through output + loss ---
__global__ __launch_bounds__(256) void vq_out_kernel(
    const float* __restrict__ z, const float* __restrict__ emb,
    const unsigned long long* __restrict__ best,
    float* __restrict__ out, float* __restrict__ lsum) {
    const int base = (blockIdx.x * 256 + threadIdx.x) * 8;   // 8 elems/thread
    const int row  = base >> 6;
    const int m    = (int)(best[row] & 0xFFFFFFFFull);

    const float4* zp = reinterpret_cast<const float4*>(z + base);
    const float4* qp = reinterpret_cast<const float4*>(emb + (size_t)m * WORD + (base & 63));
    float4* op = reinterpret_cast<float4*>(out + base);

    float s = 0.f;
#pragma unroll
    for (int i = 0; i < 2; ++i) {
        float4 zv = zp[i];
        float4 qv = qp[i];
        float dx = qv.x - zv.x, dy = qv.y - zv.y, dz = qv.z - zv.z, dw = qv.w - zv.w;
        float4 ov;
        ov.x = zv.x + dx; ov.y = zv.y + dy; ov.z = zv.z + dz; ov.w = zv.w + dw;
        op[i] = ov;
        s += dx*dx + dy*dy + dz*dz + dw*dw;
    }

#pragma unroll
    for (int off = 32; off > 0; off >>= 1) s += __shfl_down(s, off);
    __shared__ float wsum[4];
    int lane = threadIdx.x & 63, wid = threadIdx.x >> 6;
    if (lane == 0) wsum[wid] = s;
    __syncthreads();
    if (threadIdx.x == 0)
        atomicAdd(lsum, (wsum[0] + wsum[1]) + (wsum[2] + wsum[3]));
}

// ---------------- kernel 4: finalize loss -----------------------------
__global__ void vq_loss_kernel(const float* __restrict__ lsum,
                               float* __restrict__ loss_out) {
    float mean = lsum[0] * (1.0f / (float)NELEM);
    loss_out[0] = mean + 2.5f * mean;
}

extern "C" void kernel_launch(void* const* d_in, const int* in_sizes, int n_in,
                              void* d_out, int out_size, void* d_ws, size_t ws_size,
                              hipStream_t stream) {
    const float* z   = (const float*)d_in[0];   // z_mean (2048,1024)
    // d_in[1] = z_log_var, unused by the reference
    const float* emb = (const float*)d_in[2];   // (8192,64)
    float* out = (float*)d_out;                 // [z_q_st flat (2097152), loss]

    float* e2 = (float*)d_ws;
    unsigned long long* best =
        (unsigned long long*)((char*)d_ws + NB_WORD * sizeof(float));
    float* lsum = (float*)((char*)best + NROWS * sizeof(unsigned long long));

    hipMemsetAsync(lsum, 0, sizeof(float), stream);

    vq_e2_kernel<<<NB_WORD / 256, 256, 0, stream>>>(emb, e2);
    vq_argmin_kernel<<<NROWS / BM, 512, 0, stream>>>(z, emb, e2, best);
    vq_out_kernel<<<NELEM / (256 * 8), 256, 0, stream>>>(z, emb, best, out, lsum);
    vq_loss_kernel<<<1, 1, 0, stream>>>(lsum, out + NELEM);
}